// Round 13
// baseline (631.430 us; speedup 1.0000x reference)
//
#include <hip/hip_runtime.h>
#include <math.h>

typedef __attribute__((ext_vector_type(8))) _Float16 half8;
typedef __attribute__((ext_vector_type(4))) _Float16 half4;
typedef __attribute__((ext_vector_type(4))) float    floatx4;

#define N_NODES 10000
#define M_PAD   10112      // 79 * 128
#define MTILES  79
#define E_EDGES 160000
#define DIM     256
#define R_REL   237
#define L_LAYERS 6
#define B_BATCH 128
#define K_BATCH 33
#define K13     3328       // 13*256
#define WL_STRIDE 851968   // per-layer: 3*256*1024 + 256*256 halves
#define EPS_STD 1e-6f
#define EPS_LN  1e-5f

// async global->LDS, 16B per lane; LDS dest = wave-uniform base + lane*16
__device__ __forceinline__ void gload16(const void* g, void* lds) {
    __builtin_amdgcn_global_load_lds(
        (const __attribute__((address_space(1))) unsigned int*)g,
        (__attribute__((address_space(3))) unsigned int*)lds, 16, 0, 0);
}

// ---------------- CSR build ----------------
__global__ void hist_kernel(const int* __restrict__ dst, int* __restrict__ deg) {
    int e = blockIdx.x * blockDim.x + threadIdx.x;
    if (e < E_EDGES) atomicAdd(&deg[dst[e]], 1);
}

__global__ void scan_kernel(const int* __restrict__ deg_in, int* __restrict__ offs,
                            int* __restrict__ cursor, float* __restrict__ sum_log) {
    __shared__ int   part[1024];
    __shared__ float slog[1024];
    int t = threadIdx.x;
    const int CH = 10;
    int base = t * CH;
    int lsum = 0; float ls = 0.f;
    for (int j = 0; j < CH; j++) {
        int i = base + j;
        if (i < N_NODES) { int d = deg_in[i]; lsum += d; ls += logf((float)(d + 1)); }
    }
    part[t] = lsum; slog[t] = ls;
    __syncthreads();
    for (int off = 1; off < 1024; off <<= 1) {
        int v = (t >= off) ? part[t - off] : 0;
        __syncthreads();
        part[t] += v;
        __syncthreads();
    }
    int run = part[t] - lsum;
    for (int j = 0; j < CH; j++) {
        int i = base + j;
        if (i < N_NODES) { offs[i] = run; cursor[i] = run; run += deg_in[i]; }
    }
    __syncthreads();
    for (int off = 512; off > 0; off >>= 1) {
        if (t < off) slog[t] += slog[t + off];
        __syncthreads();
    }
    if (t == 0) sum_log[0] = slog[0];
}

__global__ void fill_kernel(const int* __restrict__ src, const int* __restrict__ dst,
                            const int* __restrict__ et, int* __restrict__ cursor,
                            int2* __restrict__ csr) {
    int e = blockIdx.x * blockDim.x + threadIdx.x;
    if (e < E_EDGES) {
        int d = dst[e];
        int p = atomicAdd(&cursor[d], 1);
        csr[p] = make_int2(src[e], et[e]);
    }
}

__global__ void scales_kernel(const int* __restrict__ deg_in, const float* __restrict__ sum_log,
                              float* __restrict__ s1, float* __restrict__ s2) {
    int i = blockIdx.x * blockDim.x + threadIdx.x;
    if (i < N_NODES) {
        float mean = sum_log[0] * (1.0f / (float)N_NODES);
        float sc = logf((float)(deg_in[i] + 1)) / mean;
        s1[i] = sc;
        s2[i] = 1.0f / fmaxf(sc, 0.01f);
    }
}

// -------- W permute+transpose to fp16 (scales factored OUT of the GEMM) --------
// layout per layer: [s][n][k] s=0..2, k=t*256+d (korig = k*3+s), then [n][kx] for x (korig=3072+kx)
__global__ void wt_kernel(const float* __restrict__ Ws, _Float16* __restrict__ Wt) {
    int idx = blockIdx.x * 256 + threadIdx.x;
    const int TOT = L_LAYERS * WL_STRIDE;
    if (idx >= TOT) return;
    int l = idx / WL_STRIDE;
    int r = idx - l * WL_STRIDE;
    int korig, n;
    if (r < 786432) {                 // 3*256*1024
        int sidx = r / 262144;        // 256*1024
        int r2 = r - sidx * 262144;
        n = r2 >> 10;
        int k = r2 & 1023;
        korig = k * 3 + sidx;
    } else {
        int r2 = r - 786432;
        n = r2 >> 8;
        korig = 3072 + (r2 & 255);
    }
    Wt[idx] = (_Float16)Ws[(size_t)l * K13 * 256 + (size_t)korig * 256 + n];
}

// -------- fp32 -> fp16 converter --------
__global__ void cvt_kernel(const float* __restrict__ in, _Float16* __restrict__ outp, int n) {
    int i = blockIdx.x * 256 + threadIdx.x;
    if (i < n) outp[i] = (_Float16)in[i];
}

// ---- aggregation v2: one wave per node, 4 edges/iteration (4 groups x 16 lanes, 16 dims/lane) ----
__global__ void agg_kernel(const float* __restrict__ x, const _Float16* __restrict__ xh,
                           const _Float16* __restrict__ relh,
                           const int* __restrict__ offs, const int* __restrict__ deg_in,
                           const int2* __restrict__ csr, _Float16* __restrict__ feats) {
    int wid  = threadIdx.x >> 6;
    int lane = threadIdx.x & 63;
    int node = blockIdx.x * 4 + wid;
    if (node >= N_NODES) return;
    int grp = lane >> 4;          // edge slot 0..3 (also: stat type this group writes)
    int sub = lane & 15;          // dims sub*16 .. sub*16+15
    int off = offs[node];
    int end = off + deg_in[node];
    const half8* xh8 = (const half8*)xh;
    const half8* rh8 = (const half8*)relh;

    float s_[16], q_[16], mx_[16], mn_[16];
    #pragma unroll
    for (int i = 0; i < 16; i++) { s_[i] = 0.f; q_[i] = 0.f; mx_[i] = -INFINITY; mn_[i] = INFINITY; }

    for (int base = off; base < end; base += 4) {
        int e = base + grp;
        if (e < end) {
            int2 se = csr[e];
            size_t xb = (size_t)se.x * 32 + sub * 2;
            size_t rb = (size_t)se.y * 32 + sub * 2;
            half8 xv0 = xh8[xb], xv1 = xh8[xb + 1];
            half8 rv0 = rh8[rb], rv1 = rh8[rb + 1];
            #pragma unroll
            for (int i = 0; i < 8; i++) {
                float m = (float)xv0[i] * (float)rv0[i];
                s_[i] += m; q_[i] += m * m;
                mx_[i] = fmaxf(mx_[i], m); mn_[i] = fminf(mn_[i], m);
            }
            #pragma unroll
            for (int i = 0; i < 8; i++) {
                float m = (float)xv1[i] * (float)rv1[i];
                s_[8+i] += m; q_[8+i] += m * m;
                mx_[8+i] = fmaxf(mx_[8+i], m); mn_[8+i] = fminf(mn_[8+i], m);
            }
        }
    }
    // combine the 4 groups (xor 16 flips grp bit0, xor 32 flips grp bit1)
    #pragma unroll
    for (int i = 0; i < 16; i++) {
        s_[i] += __shfl_xor(s_[i], 16);  s_[i] += __shfl_xor(s_[i], 32);
        q_[i] += __shfl_xor(q_[i], 16);  q_[i] += __shfl_xor(q_[i], 32);
        mx_[i] = fmaxf(mx_[i], __shfl_xor(mx_[i], 16));
        mx_[i] = fmaxf(mx_[i], __shfl_xor(mx_[i], 32));
        mn_[i] = fminf(mn_[i], __shfl_xor(mn_[i], 16));
        mn_[i] = fminf(mn_[i], __shfl_xor(mn_[i], 32));
    }
    // self loop message = x (fp32, exact); dims sub*16..sub*16+15
    const float4* xrow = (const float4*)(x + (size_t)node * 256);
    #pragma unroll
    for (int v = 0; v < 4; v++) {
        float4 xv = xrow[sub * 4 + v];
        float xs4[4] = {xv.x, xv.y, xv.z, xv.w};
        #pragma unroll
        for (int j = 0; j < 4; j++) {
            int i = v * 4 + j;
            s_[i] += xs4[j]; q_[i] += xs4[j] * xs4[j];
            mx_[i] = fmaxf(mx_[i], xs4[j]); mn_[i] = fminf(mn_[i], xs4[j]);
        }
    }
    float inv = 1.0f / (float)(end - off + 1);
    // group g writes stat type g (t=grp): feats[node][grp*256 + sub*16 + 0..15]
    half8 o0, o1;
    #pragma unroll
    for (int i = 0; i < 8; i++) {
        float mean = s_[i] * inv;
        float sd = sqrtf(fmaxf(q_[i] * inv - mean * mean, EPS_STD));
        o0[i] = (_Float16)((grp == 0) ? mean : (grp == 1) ? mx_[i] : (grp == 2) ? mn_[i] : sd);
    }
    #pragma unroll
    for (int i = 0; i < 8; i++) {
        float mean = s_[8+i] * inv;
        float sd = sqrtf(fmaxf(q_[8+i] * inv - mean * mean, EPS_STD));
        o1[i] = (_Float16)((grp == 0) ? mean : (grp == 1) ? mx_[8+i] : (grp == 2) ? mn_[8+i] : sd);
    }
    half8* fout = (half8*)(feats + (size_t)node * 1024 + grp * 256 + sub * 16);
    fout[0] = o0;
    fout[1] = o1;
}

// ---------------- fp16 MFMA GEMM: 4 unscaled panels (G0,G1,G2,Gx), pure gload_lds ----------------
// 128x128 tile, 2x2 waves (64x64 each), 3-buffer counted vmcnt(4).  (round-11 verbatim)
// grid = 79m * 2nh * 4panels = 632 = 8*79 (exact XCD swizzle)
__launch_bounds__(256, 3)
__global__ void gemm_kernel(const _Float16* __restrict__ feats, const _Float16* __restrict__ xh,
                            const _Float16* __restrict__ Wl, _Float16* __restrict__ hbuf) {
    __shared__ _Float16 sA[3][128 * 32];   // 24 KB
    __shared__ _Float16 sB[3][128 * 32];   // 24 KB

    int xcd = blockIdx.x & 7, loc = blockIdx.x >> 3;
    int lin = xcd * MTILES + loc;
    int sidx = lin & 3;
    int nh   = (lin >> 2) & 1;
    int m    = lin >> 3;
    const int i0 = m * 128;
    const int n0 = nh * 128;
    const int NS  = (sidx == 3) ? 8 : 32;
    const int nit = (NS - 2) / 3;

    const int tid   = threadIdx.x;
    const int lane  = tid & 63;
    const int w     = tid >> 6;
    const int wr    = w >> 1;
    const int wc    = w & 1;
    const int row_l = lane & 15;
    const int kq    = lane >> 4;

    int a_off[4], b_off[4];
    #pragma unroll
    for (int rf = 0; rf < 4; rf++) {
        int r = wr * 64 + rf * 16 + row_l;
        a_off[rf] = r * 32 + ((kq ^ ((r >> 1) & 3)) & 3) * 8;
    }
    #pragma unroll
    for (int cf = 0; cf < 4; cf++) {
        int n_ = wc * 64 + cf * 16 + row_l;
        b_off[cf] = n_ * 32 + ((kq ^ ((n_ >> 1) & 3)) & 3) * 8;
    }

    const char* a_src[2];
    const char* b_src[2];
    #pragma unroll
    for (int j = 0; j < 2; j++) {
        int rloc = j * 64 + w * 16 + (lane >> 2);
        int c = (lane & 3) ^ ((rloc >> 1) & 3);
        if (sidx < 3) {
            a_src[j] = (const char*)(feats + (size_t)(i0 + rloc) * 1024 + c * 8);
            b_src[j] = (const char*)(Wl + (size_t)sidx * 262144 + (size_t)(n0 + rloc) * 1024 + c * 8);
        } else {
            a_src[j] = (const char*)(xh + (size_t)(i0 + rloc) * 256 + c * 8);
            b_src[j] = (const char*)(Wl + 786432 + (size_t)(n0 + rloc) * 256 + c * 8);
        }
    }

    floatx4 acc[4][4];
    #pragma unroll
    for (int rf = 0; rf < 4; rf++)
        #pragma unroll
        for (int cf = 0; cf < 4; cf++)
            acc[rf][cf] = (floatx4){0.f, 0.f, 0.f, 0.f};

#define STAGE(BUF, S) do {                                                    \
    size_t koff_ = (size_t)(S) * 64;                                          \
    gload16(a_src[0] + koff_, (char*)(&sA[BUF][0]) + (0 * 64 + w * 16) * 64); \
    gload16(a_src[1] + koff_, (char*)(&sA[BUF][0]) + (1 * 64 + w * 16) * 64); \
    gload16(b_src[0] + koff_, (char*)(&sB[BUF][0]) + (0 * 64 + w * 16) * 64); \
    gload16(b_src[1] + koff_, (char*)(&sB[BUF][0]) + (1 * 64 + w * 16) * 64); \
} while (0)

#define COMPUTE(CB) do {                                                      \
    half8 af[4], bf[4];                                                       \
    _Pragma("unroll")                                                         \
    for (int rf = 0; rf < 4; rf++) af[rf] = *(const half8*)(&sA[CB][a_off[rf]]); \
    _Pragma("unroll")                                                         \
    for (int cf = 0; cf < 4; cf++) bf[cf] = *(const half8*)(&sB[CB][b_off[cf]]); \
    _Pragma("unroll")                                                         \
    for (int rf = 0; rf < 4; rf++)                                            \
        _Pragma("unroll")                                                     \
        for (int cf = 0; cf < 4; cf++)                                        \
            acc[rf][cf] = __builtin_amdgcn_mfma_f32_16x16x32_f16(af[rf], bf[cf], acc[rf][cf], 0, 0, 0); \
} while (0)

#define STEP(S, CB, NB) do {                                                  \
    asm volatile("s_waitcnt vmcnt(4)" ::: "memory");                          \
    __builtin_amdgcn_s_barrier();                                             \
    STAGE(NB, (S) + 2);                                                       \
    COMPUTE(CB);                                                              \
} while (0)

    STAGE(0, 0);
    STAGE(1, 1);

    for (int it = 0; it < nit; ++it) {
        int s = it * 3;
        STEP(s + 0, 0, 2);
        STEP(s + 1, 1, 0);
        STEP(s + 2, 2, 1);
    }
    asm volatile("s_waitcnt vmcnt(4)" ::: "memory");
    __builtin_amdgcn_s_barrier();
    COMPUTE(0);
    asm volatile("s_waitcnt vmcnt(0)" ::: "memory");
    __builtin_amdgcn_s_barrier();
    COMPUTE(1);

#undef STAGE
#undef COMPUTE
#undef STEP

    _Float16* outb = hbuf + (size_t)sidx * M_PAD * 256;
    #pragma unroll
    for (int rf = 0; rf < 4; rf++) {
        #pragma unroll
        for (int j = 0; j < 4; j++) {
            int grow = i0 + wr * 64 + rf * 16 + kq * 4 + j;
            _Float16* orow = outb + (size_t)grow * 256 + n0 + wc * 64;
            #pragma unroll
            for (int cf = 0; cf < 4; cf++)
                orow[cf * 16 + row_l] = (_Float16)acc[rf][cf][j];
        }
    }
}

// ------- panel combine (G0 + s1*G1 + s2*G2 + Gx) + bias + LN + relu + residual -------
__global__ void ln_kernel(const _Float16* __restrict__ hbuf, const float* __restrict__ xin,
                          const float* __restrict__ s1a, const float* __restrict__ s2a,
                          const float* __restrict__ bvec, const float* __restrict__ gvec,
                          const float* __restrict__ evec, float* __restrict__ xout,
                          _Float16* __restrict__ xhout) {
    int wid = threadIdx.x >> 6, lane = threadIdx.x & 63;
    int row = blockIdx.x * 4 + wid;
    if (row >= N_NODES) return;
    const half4* p0 = (const half4*)(hbuf + (size_t)row * 256);
    const half4* p1 = (const half4*)(hbuf + (size_t)M_PAD * 256     + (size_t)row * 256);
    const half4* p2 = (const half4*)(hbuf + (size_t)M_PAD * 256 * 2 + (size_t)row * 256);
    const half4* p3 = (const half4*)(hbuf + (size_t)M_PAD * 256 * 3 + (size_t)row * 256);
    half4 h0 = p0[lane], h1 = p1[lane], h2 = p2[lane], h3 = p3[lane];
    float s1v = s1a[row], s2v = s2a[row];
    float4 bv = ((const float4*)bvec)[lane];
    float4 hv;
    hv.x = (float)h0.x + s1v * (float)h1.x + s2v * (float)h2.x + (float)h3.x + bv.x;
    hv.y = (float)h0.y + s1v * (float)h1.y + s2v * (float)h2.y + (float)h3.y + bv.y;
    hv.z = (float)h0.z + s1v * (float)h1.z + s2v * (float)h2.z + (float)h3.z + bv.z;
    hv.w = (float)h0.w + s1v * (float)h1.w + s2v * (float)h2.w + (float)h3.w + bv.w;
    float s = hv.x + hv.y + hv.z + hv.w;
    float qsq = hv.x*hv.x + hv.y*hv.y + hv.z*hv.z + hv.w*hv.w;
    #pragma unroll
    for (int off = 1; off < 64; off <<= 1) {
        s   += __shfl_xor(s, off);
        qsq += __shfl_xor(qsq, off);
    }
    float mu  = s * (1.0f / 256.0f);
    float var = qsq * (1.0f / 256.0f) - mu * mu;
    float rs  = rsqrtf(var + EPS_LN);
    float4 g = ((const float4*)gvec)[lane];
    float4 e = ((const float4*)evec)[lane];
    float4 xv = ((const float4*)(xin + (size_t)row * 256))[lane];
    float4 o;
    o.x = fmaxf((hv.x - mu) * rs * g.x + e.x, 0.f) + xv.x;
    o.y = fmaxf((hv.y - mu) * rs * g.y + e.y, 0.f) + xv.y;
    o.z = fmaxf((hv.z - mu) * rs * g.z + e.z, 0.f) + xv.z;
    o.w = fmaxf((hv.w - mu) * rs * g.w + e.w, 0.f) + xv.w;
    ((float4*)(xout + (size_t)row * 256))[lane] = o;
    half4 oh = { (_Float16)o.x, (_Float16)o.y, (_Float16)o.z, (_Float16)o.w };
    ((half4*)(xhout + (size_t)row * 256))[lane] = oh;
}

// ---------------- final scoring ----------------
__global__ void score_kernel(const float* __restrict__ x, const float* __restrict__ remb,
                             const int* __restrict__ batch, float* __restrict__ out) {
    int wid = threadIdx.x >> 6, lane = threadIdx.x & 63;
    int g = blockIdx.x * 4 + wid;
    if (g >= B_BATCH * K_BATCH) return;
    int si = batch[g * 3 + 0], ri = batch[g * 3 + 1], ti = batch[g * 3 + 2];
    const float4* xs = (const float4*)(x + (size_t)si * 256);
    const float4* xr = (const float4*)(remb + (size_t)ri * 256);
    const float4* xt = (const float4*)(x + (size_t)ti * 256);
    float4 a = xs[lane], r = xr[lane], t = xt[lane];
    float p = a.x*r.x*t.x + a.y*r.y*t.y + a.z*r.z*t.z + a.w*r.w*t.w;
    #pragma unroll
    for (int off = 1; off < 64; off <<= 1) p += __shfl_xor(p, off);
    if (lane == 0) out[g] = p;
}

extern "C" void kernel_launch(void* const* d_in, const int* in_sizes, int n_in,
                              void* d_out, int out_size, void* d_ws, size_t ws_size,
                              hipStream_t stream) {
    const float* x_in     = (const float*)d_in[0];
    const float* rel_embs = (const float*)d_in[1];
    const float* Ws       = (const float*)d_in[2];
    const float* bs       = (const float*)d_in[3];
    const float* ln_s     = (const float*)d_in[4];
    const float* ln_b     = (const float*)d_in[5];
    const float* remb     = (const float*)d_in[6];
    const int*   eidx     = (const int*)d_in[7];
    const int*   etype    = (const int*)d_in[8];
    const int*   batch    = (const int*)d_in[9];
    float* out = (float*)d_out;

    char* wp = (char*)d_ws;
    size_t o = 0;
    auto alloc = [&](size_t bytes) { void* p = wp + o; o += (bytes + 255) & ~255ull; return p; };
    int*      deg_in  = (int*)     alloc((size_t)N_NODES * 4);
    int*      offs    = (int*)     alloc((size_t)N_NODES * 4);
    int*      cursor  = (int*)     alloc((size_t)N_NODES * 4);
    float*    s1      = (float*)   alloc((size_t)M_PAD * 4);
    float*    s2      = (float*)   alloc((size_t)M_PAD * 4);
    float*    sum_log = (float*)   alloc(256);
    int2*     csr     = (int2*)    alloc((size_t)E_EDGES * 8);
    _Float16* feats   = (_Float16*)alloc((size_t)M_PAD * 1024 * 2);           // 20.7 MB
    _Float16* Wt      = (_Float16*)alloc((size_t)L_LAYERS * WL_STRIDE * 2);   // 10.2 MB
    _Float16* hbuf    = (_Float16*)alloc((size_t)4 * M_PAD * 256 * 2);        // 20.7 MB
    float*    xb0     = (float*)   alloc((size_t)M_PAD * 256 * 4);
    float*    xb1     = (float*)   alloc((size_t)M_PAD * 256 * 4);
    _Float16* xh0     = (_Float16*)alloc((size_t)M_PAD * 256 * 2);
    _Float16* xh1     = (_Float16*)alloc((size_t)M_PAD * 256 * 2);
    _Float16* relh    = (_Float16*)alloc((size_t)L_LAYERS * R_REL * 256 * 2); // 0.73 MB

    const int* src  = eidx;
    const int* dstp = eidx + E_EDGES;

    hipMemsetAsync(deg_in, 0, (size_t)N_NODES * 4, stream);
    hist_kernel<<<(E_EDGES + 255) / 256, 256, 0, stream>>>(dstp, deg_in);
    scan_kernel<<<1, 1024, 0, stream>>>(deg_in, offs, cursor, sum_log);
    fill_kernel<<<(E_EDGES + 255) / 256, 256, 0, stream>>>(src, dstp, etype, cursor, csr);
    scales_kernel<<<(N_NODES + 255) / 256, 256, 0, stream>>>(deg_in, sum_log, s1, s2);
    {
        const int TOT = L_LAYERS * WL_STRIDE;
        wt_kernel<<<(TOT + 255) / 256, 256, 0, stream>>>(Ws, Wt);
        const int RT = L_LAYERS * R_REL * 256;
        cvt_kernel<<<(RT + 255) / 256, 256, 0, stream>>>(rel_embs, relh, RT);
        const int XT = N_NODES * 256;
        cvt_kernel<<<(XT + 255) / 256, 256, 0, stream>>>(x_in, xh0, XT);
    }
    hipMemcpyAsync(xb0, x_in, (size_t)N_NODES * 256 * 4, hipMemcpyDeviceToDevice, stream);

    float* xc = xb0; float* xn = xb1;
    _Float16* xhc = xh0; _Float16* xhn = xh1;
    for (int l = 0; l < L_LAYERS; l++) {
        agg_kernel<<<(N_NODES + 3) / 4, 256, 0, stream>>>(
            xc, xhc, relh + (size_t)l * R_REL * 256,
            offs, deg_in, csr, feats);
        gemm_kernel<<<632, 256, 0, stream>>>(
            feats, xhc, Wt + (size_t)l * WL_STRIDE, hbuf);
        ln_kernel<<<(N_NODES + 3) / 4, 256, 0, stream>>>(
            hbuf, xc, s1, s2, bs + (size_t)l * 256, ln_s + (size_t)l * 256,
            ln_b + (size_t)l * 256, xn, xhn);
        float* t = xc; xc = xn; xn = t;
        _Float16* th = xhc; xhc = xhn; xhn = th;
    }
    score_kernel<<<(B_BATCH * K_BATCH + 3) / 4, 256, 0, stream>>>(xc, remb, batch, out);
}

// Round 14
// 448.956 us; speedup vs baseline: 1.4064x; 1.4064x over previous
//
#include <hip/hip_runtime.h>
#include <math.h>

typedef __attribute__((ext_vector_type(8))) _Float16 half8;
typedef __attribute__((ext_vector_type(4))) _Float16 half4;
typedef __attribute__((ext_vector_type(4))) float    floatx4;

#define N_NODES 10000
#define M_PAD   10112      // 79 * 128
#define MTILES  79
#define E_EDGES 160000
#define DIM     256
#define R_REL   237
#define L_LAYERS 6
#define B_BATCH 128
#define K_BATCH 33
#define K13     3328       // 13*256
#define WL_STRIDE 851968   // per-layer: 3*256*1024 + 256*256 halves
#define EPS_STD 1e-6f
#define EPS_LN  1e-5f

// async global->LDS, 16B per lane; LDS dest = wave-uniform base + lane*16
__device__ __forceinline__ void gload16(const void* g, void* lds) {
    __builtin_amdgcn_global_load_lds(
        (const __attribute__((address_space(1))) unsigned int*)g,
        (__attribute__((address_space(3))) unsigned int*)lds, 16, 0, 0);
}

// ---------------- CSR build ----------------
__global__ void hist_kernel(const int* __restrict__ dst, int* __restrict__ deg) {
    int e = blockIdx.x * blockDim.x + threadIdx.x;
    if (e < E_EDGES) atomicAdd(&deg[dst[e]], 1);
}

__global__ void scan_kernel(const int* __restrict__ deg_in, int* __restrict__ offs,
                            int* __restrict__ cursor, float* __restrict__ sum_log) {
    __shared__ int   part[1024];
    __shared__ float slog[1024];
    int t = threadIdx.x;
    const int CH = 10;
    int base = t * CH;
    int lsum = 0; float ls = 0.f;
    for (int j = 0; j < CH; j++) {
        int i = base + j;
        if (i < N_NODES) { int d = deg_in[i]; lsum += d; ls += logf((float)(d + 1)); }
    }
    part[t] = lsum; slog[t] = ls;
    __syncthreads();
    for (int off = 1; off < 1024; off <<= 1) {
        int v = (t >= off) ? part[t - off] : 0;
        __syncthreads();
        part[t] += v;
        __syncthreads();
    }
    int run = part[t] - lsum;
    for (int j = 0; j < CH; j++) {
        int i = base + j;
        if (i < N_NODES) { offs[i] = run; cursor[i] = run; run += deg_in[i]; }
    }
    __syncthreads();
    for (int off = 512; off > 0; off >>= 1) {
        if (t < off) slog[t] += slog[t + off];
        __syncthreads();
    }
    if (t == 0) sum_log[0] = slog[0];
}

__global__ void fill_kernel(const int* __restrict__ src, const int* __restrict__ dst,
                            const int* __restrict__ et, int* __restrict__ cursor,
                            int2* __restrict__ csr) {
    int e = blockIdx.x * blockDim.x + threadIdx.x;
    if (e < E_EDGES) {
        int d = dst[e];
        int p = atomicAdd(&cursor[d], 1);
        csr[p] = make_int2(src[e], et[e]);
    }
}

__global__ void scales_kernel(const int* __restrict__ deg_in, const float* __restrict__ sum_log,
                              float* __restrict__ s1, float* __restrict__ s2) {
    int i = blockIdx.x * blockDim.x + threadIdx.x;
    if (i < N_NODES) {
        float mean = sum_log[0] * (1.0f / (float)N_NODES);
        float sc = logf((float)(deg_in[i] + 1)) / mean;
        s1[i] = sc;
        s2[i] = 1.0f / fmaxf(sc, 0.01f);
    }
}

// -------- W permute+transpose to fp16 (scales factored OUT of the GEMM) --------
// layout per layer: [s][n][k] s=0..2, k=t*256+d (korig = k*3+s), then [n][kx] for x (korig=3072+kx)
__global__ void wt_kernel(const float* __restrict__ Ws, _Float16* __restrict__ Wt) {
    int idx = blockIdx.x * 256 + threadIdx.x;
    const int TOT = L_LAYERS * WL_STRIDE;
    if (idx >= TOT) return;
    int l = idx / WL_STRIDE;
    int r = idx - l * WL_STRIDE;
    int korig, n;
    if (r < 786432) {                 // 3*256*1024
        int sidx = r / 262144;        // 256*1024
        int r2 = r - sidx * 262144;
        n = r2 >> 10;
        int k = r2 & 1023;
        korig = k * 3 + sidx;
    } else {
        int r2 = r - 786432;
        n = r2 >> 8;
        korig = 3072 + (r2 & 255);
    }
    Wt[idx] = (_Float16)Ws[(size_t)l * K13 * 256 + (size_t)korig * 256 + n];
}

// -------- fp32 -> fp16 converter --------
__global__ void cvt_kernel(const float* __restrict__ in, _Float16* __restrict__ outp, int n) {
    int i = blockIdx.x * 256 + threadIdx.x;
    if (i < n) outp[i] = (_Float16)in[i];
}

// ---- aggregation: one wave per node, 2 edges/iteration (lane halves), fp16 gather ----
// 32 accumulator VGPRs per lane (fits registers; round-13's 64 spilled to scratch)
__global__ void agg_kernel(const float* __restrict__ x, const _Float16* __restrict__ xh,
                           const _Float16* __restrict__ relh,
                           const int* __restrict__ offs, const int* __restrict__ deg_in,
                           const int2* __restrict__ csr, _Float16* __restrict__ feats) {
    int wid  = threadIdx.x >> 6;
    int lane = threadIdx.x & 63;
    int node = blockIdx.x * 4 + wid;
    if (node >= N_NODES) return;
    int half = lane >> 5;         // 0: even edges, 1: odd edges
    int sub  = lane & 31;         // 8-dim chunk owner: dims sub*8..sub*8+7
    int off = offs[node];
    int end = off + deg_in[node];
    const half8* xh8 = (const half8*)xh;
    const half8* rh8 = (const half8*)relh;

    float s_[8], q_[8], mx_[8], mn_[8];
    #pragma unroll
    for (int i = 0; i < 8; i++) { s_[i] = 0.f; q_[i] = 0.f; mx_[i] = -INFINITY; mn_[i] = INFINITY; }

    for (int base = off; base < end; base += 2) {
        int e = base + half;
        if (e < end) {
            int2 se = csr[e];
            half8 xv = xh8[(size_t)se.x * 32 + sub];
            half8 rv = rh8[(size_t)se.y * 32 + sub];
            half8 mv = xv * rv;                       // packed fp16 multiply (4 v_pk_mul_f16)
            #pragma unroll
            for (int i = 0; i < 8; i++) {
                float m = (float)mv[i];
                s_[i] += m; q_[i] += m * m;
                mx_[i] = fmaxf(mx_[i], m);
                mn_[i] = fminf(mn_[i], m);
            }
        }
    }
    // combine halves (both halves end up with full stats)
    #pragma unroll
    for (int i = 0; i < 8; i++) {
        s_[i] += __shfl_xor(s_[i], 32);
        q_[i] += __shfl_xor(q_[i], 32);
        mx_[i] = fmaxf(mx_[i], __shfl_xor(mx_[i], 32));
        mn_[i] = fminf(mn_[i], __shfl_xor(mn_[i], 32));
    }
    // self loop message = x (fp32, exact); dims sub*8..sub*8+7
    const float4* xrow = (const float4*)(x + (size_t)node * 256);
    float4 xa = xrow[sub * 2], xb = xrow[sub * 2 + 1];
    float xs[8] = {xa.x, xa.y, xa.z, xa.w, xb.x, xb.y, xb.z, xb.w};
    #pragma unroll
    for (int i = 0; i < 8; i++) {
        s_[i] += xs[i]; q_[i] += xs[i] * xs[i];
        mx_[i] = fmaxf(mx_[i], xs[i]);
        mn_[i] = fminf(mn_[i], xs[i]);
    }
    float inv = 1.0f / (float)(end - off + 1);
    half8 hm, hx, hn, hs;
    #pragma unroll
    for (int i = 0; i < 8; i++) {
        float mean = s_[i] * inv;
        float sd = sqrtf(fmaxf(q_[i] * inv - mean * mean, EPS_STD));
        hm[i] = (_Float16)mean; hx[i] = (_Float16)mx_[i];
        hn[i] = (_Float16)mn_[i]; hs[i] = (_Float16)sd;
    }
    half8* fout = (half8*)(feats + (size_t)node * 1024);
    if (half == 0) {
        fout[0 * 32 + sub] = hm;   // t=0 mean
        fout[1 * 32 + sub] = hx;   // t=1 max
    } else {
        fout[2 * 32 + sub] = hn;   // t=2 min
        fout[3 * 32 + sub] = hs;   // t=3 std
    }
}

// ---------------- fp16 MFMA GEMM: 4 unscaled panels (G0,G1,G2,Gx), pure gload_lds ----------------
// 128x128 tile, 2x2 waves (64x64 each), 3-buffer counted vmcnt(4).  (round-11 verbatim)
// grid = 79m * 2nh * 4panels = 632 = 8*79 (exact XCD swizzle)
__launch_bounds__(256, 3)
__global__ void gemm_kernel(const _Float16* __restrict__ feats, const _Float16* __restrict__ xh,
                            const _Float16* __restrict__ Wl, _Float16* __restrict__ hbuf) {
    __shared__ _Float16 sA[3][128 * 32];   // 24 KB
    __shared__ _Float16 sB[3][128 * 32];   // 24 KB

    int xcd = blockIdx.x & 7, loc = blockIdx.x >> 3;
    int lin = xcd * MTILES + loc;
    int sidx = lin & 3;
    int nh   = (lin >> 2) & 1;
    int m    = lin >> 3;
    const int i0 = m * 128;
    const int n0 = nh * 128;
    const int NS  = (sidx == 3) ? 8 : 32;
    const int nit = (NS - 2) / 3;

    const int tid   = threadIdx.x;
    const int lane  = tid & 63;
    const int w     = tid >> 6;
    const int wr    = w >> 1;
    const int wc    = w & 1;
    const int row_l = lane & 15;
    const int kq    = lane >> 4;

    int a_off[4], b_off[4];
    #pragma unroll
    for (int rf = 0; rf < 4; rf++) {
        int r = wr * 64 + rf * 16 + row_l;
        a_off[rf] = r * 32 + ((kq ^ ((r >> 1) & 3)) & 3) * 8;
    }
    #pragma unroll
    for (int cf = 0; cf < 4; cf++) {
        int n_ = wc * 64 + cf * 16 + row_l;
        b_off[cf] = n_ * 32 + ((kq ^ ((n_ >> 1) & 3)) & 3) * 8;
    }

    const char* a_src[2];
    const char* b_src[2];
    #pragma unroll
    for (int j = 0; j < 2; j++) {
        int rloc = j * 64 + w * 16 + (lane >> 2);
        int c = (lane & 3) ^ ((rloc >> 1) & 3);
        if (sidx < 3) {
            a_src[j] = (const char*)(feats + (size_t)(i0 + rloc) * 1024 + c * 8);
            b_src[j] = (const char*)(Wl + (size_t)sidx * 262144 + (size_t)(n0 + rloc) * 1024 + c * 8);
        } else {
            a_src[j] = (const char*)(xh + (size_t)(i0 + rloc) * 256 + c * 8);
            b_src[j] = (const char*)(Wl + 786432 + (size_t)(n0 + rloc) * 256 + c * 8);
        }
    }

    floatx4 acc[4][4];
    #pragma unroll
    for (int rf = 0; rf < 4; rf++)
        #pragma unroll
        for (int cf = 0; cf < 4; cf++)
            acc[rf][cf] = (floatx4){0.f, 0.f, 0.f, 0.f};

#define STAGE(BUF, S) do {                                                    \
    size_t koff_ = (size_t)(S) * 64;                                          \
    gload16(a_src[0] + koff_, (char*)(&sA[BUF][0]) + (0 * 64 + w * 16) * 64); \
    gload16(a_src[1] + koff_, (char*)(&sA[BUF][0]) + (1 * 64 + w * 16) * 64); \
    gload16(b_src[0] + koff_, (char*)(&sB[BUF][0]) + (0 * 64 + w * 16) * 64); \
    gload16(b_src[1] + koff_, (char*)(&sB[BUF][0]) + (1 * 64 + w * 16) * 64); \
} while (0)

#define COMPUTE(CB) do {                                                      \
    half8 af[4], bf[4];                                                       \
    _Pragma("unroll")                                                         \
    for (int rf = 0; rf < 4; rf++) af[rf] = *(const half8*)(&sA[CB][a_off[rf]]); \
    _Pragma("unroll")                                                         \
    for (int cf = 0; cf < 4; cf++) bf[cf] = *(const half8*)(&sB[CB][b_off[cf]]); \
    _Pragma("unroll")                                                         \
    for (int rf = 0; rf < 4; rf++)                                            \
        _Pragma("unroll")                                                     \
        for (int cf = 0; cf < 4; cf++)                                        \
            acc[rf][cf] = __builtin_amdgcn_mfma_f32_16x16x32_f16(af[rf], bf[cf], acc[rf][cf], 0, 0, 0); \
} while (0)

#define STEP(S, CB, NB) do {                                                  \
    asm volatile("s_waitcnt vmcnt(4)" ::: "memory");                          \
    __builtin_amdgcn_s_barrier();                                             \
    STAGE(NB, (S) + 2);                                                       \
    COMPUTE(CB);                                                              \
} while (0)

    STAGE(0, 0);
    STAGE(1, 1);

    for (int it = 0; it < nit; ++it) {
        int s = it * 3;
        STEP(s + 0, 0, 2);
        STEP(s + 1, 1, 0);
        STEP(s + 2, 2, 1);
    }
    asm volatile("s_waitcnt vmcnt(4)" ::: "memory");
    __builtin_amdgcn_s_barrier();
    COMPUTE(0);
    asm volatile("s_waitcnt vmcnt(0)" ::: "memory");
    __builtin_amdgcn_s_barrier();
    COMPUTE(1);

#undef STAGE
#undef COMPUTE
#undef STEP

    _Float16* outb = hbuf + (size_t)sidx * M_PAD * 256;
    #pragma unroll
    for (int rf = 0; rf < 4; rf++) {
        #pragma unroll
        for (int j = 0; j < 4; j++) {
            int grow = i0 + wr * 64 + rf * 16 + kq * 4 + j;
            _Float16* orow = outb + (size_t)grow * 256 + n0 + wc * 64;
            #pragma unroll
            for (int cf = 0; cf < 4; cf++)
                orow[cf * 16 + row_l] = (_Float16)acc[rf][cf][j];
        }
    }
}

// ------- panel combine (G0 + s1*G1 + s2*G2 + Gx) + bias + LN + relu + residual -------
__global__ void ln_kernel(const _Float16* __restrict__ hbuf, const float* __restrict__ xin,
                          const float* __restrict__ s1a, const float* __restrict__ s2a,
                          const float* __restrict__ bvec, const float* __restrict__ gvec,
                          const float* __restrict__ evec, float* __restrict__ xout,
                          _Float16* __restrict__ xhout) {
    int wid = threadIdx.x >> 6, lane = threadIdx.x & 63;
    int row = blockIdx.x * 4 + wid;
    if (row >= N_NODES) return;
    const half4* p0 = (const half4*)(hbuf + (size_t)row * 256);
    const half4* p1 = (const half4*)(hbuf + (size_t)M_PAD * 256     + (size_t)row * 256);
    const half4* p2 = (const half4*)(hbuf + (size_t)M_PAD * 256 * 2 + (size_t)row * 256);
    const half4* p3 = (const half4*)(hbuf + (size_t)M_PAD * 256 * 3 + (size_t)row * 256);
    half4 h0 = p0[lane], h1 = p1[lane], h2 = p2[lane], h3 = p3[lane];
    float s1v = s1a[row], s2v = s2a[row];
    float4 bv = ((const float4*)bvec)[lane];
    float4 hv;
    hv.x = (float)h0.x + s1v * (float)h1.x + s2v * (float)h2.x + (float)h3.x + bv.x;
    hv.y = (float)h0.y + s1v * (float)h1.y + s2v * (float)h2.y + (float)h3.y + bv.y;
    hv.z = (float)h0.z + s1v * (float)h1.z + s2v * (float)h2.z + (float)h3.z + bv.z;
    hv.w = (float)h0.w + s1v * (float)h1.w + s2v * (float)h2.w + (float)h3.w + bv.w;
    float s = hv.x + hv.y + hv.z + hv.w;
    float qsq = hv.x*hv.x + hv.y*hv.y + hv.z*hv.z + hv.w*hv.w;
    #pragma unroll
    for (int off = 1; off < 64; off <<= 1) {
        s   += __shfl_xor(s, off);
        qsq += __shfl_xor(qsq, off);
    }
    float mu  = s * (1.0f / 256.0f);
    float var = qsq * (1.0f / 256.0f) - mu * mu;
    float rs  = rsqrtf(var + EPS_LN);
    float4 g = ((const float4*)gvec)[lane];
    float4 e = ((const float4*)evec)[lane];
    float4 xv = ((const float4*)(xin + (size_t)row * 256))[lane];
    float4 o;
    o.x = fmaxf((hv.x - mu) * rs * g.x + e.x, 0.f) + xv.x;
    o.y = fmaxf((hv.y - mu) * rs * g.y + e.y, 0.f) + xv.y;
    o.z = fmaxf((hv.z - mu) * rs * g.z + e.z, 0.f) + xv.z;
    o.w = fmaxf((hv.w - mu) * rs * g.w + e.w, 0.f) + xv.w;
    ((float4*)(xout + (size_t)row * 256))[lane] = o;
    half4 oh = { (_Float16)o.x, (_Float16)o.y, (_Float16)o.z, (_Float16)o.w };
    ((half4*)(xhout + (size_t)row * 256))[lane] = oh;
}

// ---------------- final scoring ----------------
__global__ void score_kernel(const float* __restrict__ x, const float* __restrict__ remb,
                             const int* __restrict__ batch, float* __restrict__ out) {
    int wid = threadIdx.x >> 6, lane = threadIdx.x & 63;
    int g = blockIdx.x * 4 + wid;
    if (g >= B_BATCH * K_BATCH) return;
    int si = batch[g * 3 + 0], ri = batch[g * 3 + 1], ti = batch[g * 3 + 2];
    const float4* xs = (const float4*)(x + (size_t)si * 256);
    const float4* xr = (const float4*)(remb + (size_t)ri * 256);
    const float4* xt = (const float4*)(x + (size_t)ti * 256);
    float4 a = xs[lane], r = xr[lane], t = xt[lane];
    float p = a.x*r.x*t.x + a.y*r.y*t.y + a.z*r.z*t.z + a.w*r.w*t.w;
    #pragma unroll
    for (int off = 1; off < 64; off <<= 1) p += __shfl_xor(p, off);
    if (lane == 0) out[g] = p;
}

extern "C" void kernel_launch(void* const* d_in, const int* in_sizes, int n_in,
                              void* d_out, int out_size, void* d_ws, size_t ws_size,
                              hipStream_t stream) {
    const float* x_in     = (const float*)d_in[0];
    const float* rel_embs = (const float*)d_in[1];
    const float* Ws       = (const float*)d_in[2];
    const float* bs       = (const float*)d_in[3];
    const float* ln_s     = (const float*)d_in[4];
    const float* ln_b     = (const float*)d_in[5];
    const float* remb     = (const float*)d_in[6];
    const int*   eidx     = (const int*)d_in[7];
    const int*   etype    = (const int*)d_in[8];
    const int*   batch    = (const int*)d_in[9];
    float* out = (float*)d_out;

    char* wp = (char*)d_ws;
    size_t o = 0;
    auto alloc = [&](size_t bytes) { void* p = wp + o; o += (bytes + 255) & ~255ull; return p; };
    int*      deg_in  = (int*)     alloc((size_t)N_NODES * 4);
    int*      offs    = (int*)     alloc((size_t)N_NODES * 4);
    int*      cursor  = (int*)     alloc((size_t)N_NODES * 4);
    float*    s1      = (float*)   alloc((size_t)M_PAD * 4);
    float*    s2      = (float*)   alloc((size_t)M_PAD * 4);
    float*    sum_log = (float*)   alloc(256);
    int2*     csr     = (int2*)    alloc((size_t)E_EDGES * 8);
    _Float16* feats   = (_Float16*)alloc((size_t)M_PAD * 1024 * 2);           // 20.7 MB
    _Float16* Wt      = (_Float16*)alloc((size_t)L_LAYERS * WL_STRIDE * 2);   // 10.2 MB
    _Float16* hbuf    = (_Float16*)alloc((size_t)4 * M_PAD * 256 * 2);        // 20.7 MB
    float*    xb0     = (float*)   alloc((size_t)M_PAD * 256 * 4);
    float*    xb1     = (float*)   alloc((size_t)M_PAD * 256 * 4);
    _Float16* xh0     = (_Float16*)alloc((size_t)M_PAD * 256 * 2);
    _Float16* xh1     = (_Float16*)alloc((size_t)M_PAD * 256 * 2);
    _Float16* relh    = (_Float16*)alloc((size_t)L_LAYERS * R_REL * 256 * 2); // 0.73 MB

    const int* src  = eidx;
    const int* dstp = eidx + E_EDGES;

    hipMemsetAsync(deg_in, 0, (size_t)N_NODES * 4, stream);
    hist_kernel<<<(E_EDGES + 255) / 256, 256, 0, stream>>>(dstp, deg_in);
    scan_kernel<<<1, 1024, 0, stream>>>(deg_in, offs, cursor, sum_log);
    fill_kernel<<<(E_EDGES + 255) / 256, 256, 0, stream>>>(src, dstp, etype, cursor, csr);
    scales_kernel<<<(N_NODES + 255) / 256, 256, 0, stream>>>(deg_in, sum_log, s1, s2);
    {
        const int TOT = L_LAYERS * WL_STRIDE;
        wt_kernel<<<(TOT + 255) / 256, 256, 0, stream>>>(Ws, Wt);
        const int RT = L_LAYERS * R_REL * 256;
        cvt_kernel<<<(RT + 255) / 256, 256, 0, stream>>>(rel_embs, relh, RT);
        const int XT = N_NODES * 256;
        cvt_kernel<<<(XT + 255) / 256, 256, 0, stream>>>(x_in, xh0, XT);
    }
    hipMemcpyAsync(xb0, x_in, (size_t)N_NODES * 256 * 4, hipMemcpyDeviceToDevice, stream);

    float* xc = xb0; float* xn = xb1;
    _Float16* xhc = xh0; _Float16* xhn = xh1;
    for (int l = 0; l < L_LAYERS; l++) {
        agg_kernel<<<(N_NODES + 3) / 4, 256, 0, stream>>>(
            xc, xhc, relh + (size_t)l * R_REL * 256,
            offs, deg_in, csr, feats);
        gemm_kernel<<<632, 256, 0, stream>>>(
            feats, xhc, Wt + (size_t)l * WL_STRIDE, hbuf);
        ln_kernel<<<(N_NODES + 3) / 4, 256, 0, stream>>>(
            hbuf, xc, s1, s2, bs + (size_t)l * 256, ln_s + (size_t)l * 256,
            ln_b + (size_t)l * 256, xn, xhn);
        float* t = xc; xc = xn; xn = t;
        _Float16* th = xhc; xhc = xhn; xhn = th;
    }
    score_kernel<<<(B_BATCH * K_BATCH + 3) / 4, 256, 0, stream>>>(xc, remb, batch, out);
}

// Round 15
// 434.015 us; speedup vs baseline: 1.4549x; 1.0344x over previous
//
#include <hip/hip_runtime.h>
#include <math.h>

typedef __attribute__((ext_vector_type(8))) _Float16 half8;
typedef __attribute__((ext_vector_type(4))) _Float16 half4;
typedef __attribute__((ext_vector_type(4))) float    floatx4;
typedef __attribute__((ext_vector_type(2))) float    float2v;

#define N_NODES 10000
#define M_PAD   10112      // 79 * 128
#define MTILES  79
#define E_EDGES 160000
#define DIM     256
#define R_REL   237
#define L_LAYERS 6
#define B_BATCH 128
#define K_BATCH 33
#define K13     3328       // 13*256
#define WL_STRIDE 851968   // per-layer: 3*256*1024 + 256*256 halves
#define EPS_STD 1e-6f
#define EPS_LN  1e-5f

// async global->LDS, 16B per lane; LDS dest = wave-uniform base + lane*16
__device__ __forceinline__ void gload16(const void* g, void* lds) {
    __builtin_amdgcn_global_load_lds(
        (const __attribute__((address_space(1))) unsigned int*)g,
        (__attribute__((address_space(3))) unsigned int*)lds, 16, 0, 0);
}

// packed fp16 max/min (exact; scheduler-friendly non-volatile asm)
__device__ __forceinline__ unsigned pkmax16(unsigned a, unsigned b) {
    unsigned r;
    asm("v_pk_max_f16 %0, %1, %2" : "=v"(r) : "v"(a), "v"(b));
    return r;
}
__device__ __forceinline__ unsigned pkmin16(unsigned a, unsigned b) {
    unsigned r;
    asm("v_pk_min_f16 %0, %1, %2" : "=v"(r) : "v"(a), "v"(b));
    return r;
}
typedef union { half8 h; unsigned u[4]; } h8u;

// ---------------- CSR build ----------------
__global__ void hist_kernel(const int* __restrict__ dst, int* __restrict__ deg) {
    int e = blockIdx.x * blockDim.x + threadIdx.x;
    if (e < E_EDGES) atomicAdd(&deg[dst[e]], 1);
}

__global__ void scan_kernel(const int* __restrict__ deg_in, int* __restrict__ offs,
                            int* __restrict__ cursor, float* __restrict__ sum_log) {
    __shared__ int   part[1024];
    __shared__ float slog[1024];
    int t = threadIdx.x;
    const int CH = 10;
    int base = t * CH;
    int lsum = 0; float ls = 0.f;
    for (int j = 0; j < CH; j++) {
        int i = base + j;
        if (i < N_NODES) { int d = deg_in[i]; lsum += d; ls += logf((float)(d + 1)); }
    }
    part[t] = lsum; slog[t] = ls;
    __syncthreads();
    for (int off = 1; off < 1024; off <<= 1) {
        int v = (t >= off) ? part[t - off] : 0;
        __syncthreads();
        part[t] += v;
        __syncthreads();
    }
    int run = part[t] - lsum;
    for (int j = 0; j < CH; j++) {
        int i = base + j;
        if (i < N_NODES) { offs[i] = run; cursor[i] = run; run += deg_in[i]; }
    }
    __syncthreads();
    for (int off = 512; off > 0; off >>= 1) {
        if (t < off) slog[t] += slog[t + off];
        __syncthreads();
    }
    if (t == 0) sum_log[0] = slog[0];
}

__global__ void fill_kernel(const int* __restrict__ src, const int* __restrict__ dst,
                            const int* __restrict__ et, int* __restrict__ cursor,
                            int2* __restrict__ csr) {
    int e = blockIdx.x * blockDim.x + threadIdx.x;
    if (e < E_EDGES) {
        int d = dst[e];
        int p = atomicAdd(&cursor[d], 1);
        csr[p] = make_int2(src[e], et[e]);
    }
}

__global__ void scales_kernel(const int* __restrict__ deg_in, const float* __restrict__ sum_log,
                              float* __restrict__ s1, float* __restrict__ s2) {
    int i = blockIdx.x * blockDim.x + threadIdx.x;
    if (i < N_NODES) {
        float mean = sum_log[0] * (1.0f / (float)N_NODES);
        float sc = logf((float)(deg_in[i] + 1)) / mean;
        s1[i] = sc;
        s2[i] = 1.0f / fmaxf(sc, 0.01f);
    }
}

// -------- W permute+transpose to fp16 (scales factored OUT of the GEMM) --------
__global__ void wt_kernel(const float* __restrict__ Ws, _Float16* __restrict__ Wt) {
    int idx = blockIdx.x * 256 + threadIdx.x;
    const int TOT = L_LAYERS * WL_STRIDE;
    if (idx >= TOT) return;
    int l = idx / WL_STRIDE;
    int r = idx - l * WL_STRIDE;
    int korig, n;
    if (r < 786432) {                 // 3*256*1024
        int sidx = r / 262144;        // 256*1024
        int r2 = r - sidx * 262144;
        n = r2 >> 10;
        int k = r2 & 1023;
        korig = k * 3 + sidx;
    } else {
        int r2 = r - 786432;
        n = r2 >> 8;
        korig = 3072 + (r2 & 255);
    }
    Wt[idx] = (_Float16)Ws[(size_t)l * K13 * 256 + (size_t)korig * 256 + n];
}

// -------- fp32 -> fp16 converter --------
__global__ void cvt_kernel(const float* __restrict__ in, _Float16* __restrict__ outp, int n) {
    int i = blockIdx.x * 256 + threadIdx.x;
    if (i < n) outp[i] = (_Float16)in[i];
}

// ---- aggregation v3: one wave per node, 2 edges/iter, BRANCHLESS main loop ----
// packed fp16 minmax (asm), float2 s/q (pk_f32), odd tail once at weight 0.5 (exact)
__global__ void agg_kernel(const float* __restrict__ x, const _Float16* __restrict__ xh,
                           const _Float16* __restrict__ relh,
                           const int* __restrict__ offs, const int* __restrict__ deg_in,
                           const int2* __restrict__ csr, _Float16* __restrict__ feats) {
    int wid  = threadIdx.x >> 6;
    int lane = threadIdx.x & 63;
    int node = blockIdx.x * 4 + wid;
    if (node >= N_NODES) return;
    int half = lane >> 5;         // 0: even edges, 1: odd edges
    int sub  = lane & 31;         // 8-dim chunk: dims sub*8..sub*8+7
    int off = offs[node];
    int dc  = deg_in[node];
    int npairs = dc >> 1;         // wave-uniform trip count
    const half8* xh8 = (const half8*)xh;
    const half8* rh8 = (const half8*)relh;

    float2v s2[4], q2[4];
    unsigned mxu[4], mnu[4];
    #pragma unroll
    for (int i = 0; i < 4; i++) {
        s2[i] = (float2v){0.f, 0.f};
        q2[i] = (float2v){0.f, 0.f};
        mxu[i] = 0xFC00FC00u;     // (-inf,-inf) fp16
        mnu[i] = 0x7C007C00u;     // (+inf,+inf) fp16
    }

    const int2* ep = csr + off + half;
    for (int p = 0; p < npairs; p++) {
        int2 se = ep[2 * p];
        half8 xv = xh8[(size_t)se.x * 32 + sub];
        half8 rv = rh8[(size_t)se.y * 32 + sub];
        half8 mv = xv * rv;                         // v_pk_mul_f16 x4
        h8u mu; mu.h = mv;
        #pragma unroll
        for (int i = 0; i < 4; i++) {
            mxu[i] = pkmax16(mxu[i], mu.u[i]);
            mnu[i] = pkmin16(mnu[i], mu.u[i]);
            float2v mf = { (float)mv[2*i], (float)mv[2*i+1] };
            s2[i] += mf;                            // v_pk_add_f32
            q2[i] += mf * mf;                       // v_pk_fma_f32
        }
    }
    if (dc & 1) {   // wave-uniform: both halves process edge (off+dc-1) at weight 0.5
        int2 se = csr[off + dc - 1];
        half8 xv = xh8[(size_t)se.x * 32 + sub];
        half8 rv = rh8[(size_t)se.y * 32 + sub];
        half8 mv = xv * rv;
        h8u mu; mu.h = mv;
        #pragma unroll
        for (int i = 0; i < 4; i++) {
            mxu[i] = pkmax16(mxu[i], mu.u[i]);      // duplicate across halves: harmless
            mnu[i] = pkmin16(mnu[i], mu.u[i]);
            float2v mf = { (float)mv[2*i], (float)mv[2*i+1] };
            s2[i] += 0.5f * mf;                     // 0.5+0.5 across halves = exact
            q2[i] += (0.5f * mf) * mf;
        }
    }
    // combine halves
    float s_[8], q_[8], mx_[8], mn_[8];
    #pragma unroll
    for (int i = 0; i < 4; i++) {
        mxu[i] = pkmax16(mxu[i], (unsigned)__shfl_xor((int)mxu[i], 32));
        mnu[i] = pkmin16(mnu[i], (unsigned)__shfl_xor((int)mnu[i], 32));
        h8u tx; tx.u[0] = mxu[i]; h8u tn; tn.u[0] = mnu[i];
        mx_[2*i]   = (float)tx.h[0]; mx_[2*i+1] = (float)tx.h[1];
        mn_[2*i]   = (float)tn.h[0]; mn_[2*i+1] = (float)tn.h[1];
        s_[2*i]   = s2[i].x + __shfl_xor(s2[i].x, 32);
        s_[2*i+1] = s2[i].y + __shfl_xor(s2[i].y, 32);
        q_[2*i]   = q2[i].x + __shfl_xor(q2[i].x, 32);
        q_[2*i+1] = q2[i].y + __shfl_xor(q2[i].y, 32);
    }
    // self loop message = x (fp32, exact); dims sub*8..sub*8+7
    const float4* xrow = (const float4*)(x + (size_t)node * 256);
    float4 xa = xrow[sub * 2], xb = xrow[sub * 2 + 1];
    float xs[8] = {xa.x, xa.y, xa.z, xa.w, xb.x, xb.y, xb.z, xb.w};
    #pragma unroll
    for (int i = 0; i < 8; i++) {
        s_[i] += xs[i]; q_[i] += xs[i] * xs[i];
        mx_[i] = fmaxf(mx_[i], xs[i]);
        mn_[i] = fminf(mn_[i], xs[i]);
    }
    float inv = 1.0f / (float)(dc + 1);
    half8 hm, hx, hn, hs;
    #pragma unroll
    for (int i = 0; i < 8; i++) {
        float mean = s_[i] * inv;
        float sd = sqrtf(fmaxf(q_[i] * inv - mean * mean, EPS_STD));
        hm[i] = (_Float16)mean; hx[i] = (_Float16)mx_[i];
        hn[i] = (_Float16)mn_[i]; hs[i] = (_Float16)sd;
    }
    half8* fout = (half8*)(feats + (size_t)node * 1024);
    if (half == 0) {
        fout[0 * 32 + sub] = hm;   // t=0 mean
        fout[1 * 32 + sub] = hx;   // t=1 max
    } else {
        fout[2 * 32 + sub] = hn;   // t=2 min
        fout[3 * 32 + sub] = hs;   // t=3 std
    }
}

// ---------------- fp16 MFMA GEMM: 4 unscaled panels (G0,G1,G2,Gx), pure gload_lds ----------------
// 128x128 tile, 2x2 waves (64x64 each), 3-buffer counted vmcnt(4).  (round-11 verbatim)
__launch_bounds__(256, 3)
__global__ void gemm_kernel(const _Float16* __restrict__ feats, const _Float16* __restrict__ xh,
                            const _Float16* __restrict__ Wl, _Float16* __restrict__ hbuf) {
    __shared__ _Float16 sA[3][128 * 32];   // 24 KB
    __shared__ _Float16 sB[3][128 * 32];   // 24 KB

    int xcd = blockIdx.x & 7, loc = blockIdx.x >> 3;
    int lin = xcd * MTILES + loc;
    int sidx = lin & 3;
    int nh   = (lin >> 2) & 1;
    int m    = lin >> 3;
    const int i0 = m * 128;
    const int n0 = nh * 128;
    const int NS  = (sidx == 3) ? 8 : 32;
    const int nit = (NS - 2) / 3;

    const int tid   = threadIdx.x;
    const int lane  = tid & 63;
    const int w     = tid >> 6;
    const int wr    = w >> 1;
    const int wc    = w & 1;
    const int row_l = lane & 15;
    const int kq    = lane >> 4;

    int a_off[4], b_off[4];
    #pragma unroll
    for (int rf = 0; rf < 4; rf++) {
        int r = wr * 64 + rf * 16 + row_l;
        a_off[rf] = r * 32 + ((kq ^ ((r >> 1) & 3)) & 3) * 8;
    }
    #pragma unroll
    for (int cf = 0; cf < 4; cf++) {
        int n_ = wc * 64 + cf * 16 + row_l;
        b_off[cf] = n_ * 32 + ((kq ^ ((n_ >> 1) & 3)) & 3) * 8;
    }

    const char* a_src[2];
    const char* b_src[2];
    #pragma unroll
    for (int j = 0; j < 2; j++) {
        int rloc = j * 64 + w * 16 + (lane >> 2);
        int c = (lane & 3) ^ ((rloc >> 1) & 3);
        if (sidx < 3) {
            a_src[j] = (const char*)(feats + (size_t)(i0 + rloc) * 1024 + c * 8);
            b_src[j] = (const char*)(Wl + (size_t)sidx * 262144 + (size_t)(n0 + rloc) * 1024 + c * 8);
        } else {
            a_src[j] = (const char*)(xh + (size_t)(i0 + rloc) * 256 + c * 8);
            b_src[j] = (const char*)(Wl + 786432 + (size_t)(n0 + rloc) * 256 + c * 8);
        }
    }

    floatx4 acc[4][4];
    #pragma unroll
    for (int rf = 0; rf < 4; rf++)
        #pragma unroll
        for (int cf = 0; cf < 4; cf++)
            acc[rf][cf] = (floatx4){0.f, 0.f, 0.f, 0.f};

#define STAGE(BUF, S) do {                                                    \
    size_t koff_ = (size_t)(S) * 64;                                          \
    gload16(a_src[0] + koff_, (char*)(&sA[BUF][0]) + (0 * 64 + w * 16) * 64); \
    gload16(a_src[1] + koff_, (char*)(&sA[BUF][0]) + (1 * 64 + w * 16) * 64); \
    gload16(b_src[0] + koff_, (char*)(&sB[BUF][0]) + (0 * 64 + w * 16) * 64); \
    gload16(b_src[1] + koff_, (char*)(&sB[BUF][0]) + (1 * 64 + w * 16) * 64); \
} while (0)

#define COMPUTE(CB) do {                                                      \
    half8 af[4], bf[4];                                                       \
    _Pragma("unroll")                                                         \
    for (int rf = 0; rf < 4; rf++) af[rf] = *(const half8*)(&sA[CB][a_off[rf]]); \
    _Pragma("unroll")                                                         \
    for (int cf = 0; cf < 4; cf++) bf[cf] = *(const half8*)(&sB[CB][b_off[cf]]); \
    _Pragma("unroll")                                                         \
    for (int rf = 0; rf < 4; rf++)                                            \
        _Pragma("unroll")                                                     \
        for (int cf = 0; cf < 4; cf++)                                        \
            acc[rf][cf] = __builtin_amdgcn_mfma_f32_16x16x32_f16(af[rf], bf[cf], acc[rf][cf], 0, 0, 0); \
} while (0)

#define STEP(S, CB, NB) do {                                                  \
    asm volatile("s_waitcnt vmcnt(4)" ::: "memory");                          \
    __builtin_amdgcn_s_barrier();                                             \
    STAGE(NB, (S) + 2);                                                       \
    COMPUTE(CB);                                                              \
} while (0)

    STAGE(0, 0);
    STAGE(1, 1);

    for (int it = 0; it < nit; ++it) {
        int s = it * 3;
        STEP(s + 0, 0, 2);
        STEP(s + 1, 1, 0);
        STEP(s + 2, 2, 1);
    }
    asm volatile("s_waitcnt vmcnt(4)" ::: "memory");
    __builtin_amdgcn_s_barrier();
    COMPUTE(0);
    asm volatile("s_waitcnt vmcnt(0)" ::: "memory");
    __builtin_amdgcn_s_barrier();
    COMPUTE(1);

#undef STAGE
#undef COMPUTE
#undef STEP

    _Float16* outb = hbuf + (size_t)sidx * M_PAD * 256;
    #pragma unroll
    for (int rf = 0; rf < 4; rf++) {
        #pragma unroll
        for (int j = 0; j < 4; j++) {
            int grow = i0 + wr * 64 + rf * 16 + kq * 4 + j;
            _Float16* orow = outb + (size_t)grow * 256 + n0 + wc * 64;
            #pragma unroll
            for (int cf = 0; cf < 4; cf++)
                orow[cf * 16 + row_l] = (_Float16)acc[rf][cf][j];
        }
    }
}

// ------- panel combine (G0 + s1*G1 + s2*G2 + Gx) + bias + LN + relu + residual -------
__global__ void ln_kernel(const _Float16* __restrict__ hbuf, const float* __restrict__ xin,
                          const float* __restrict__ s1a, const float* __restrict__ s2a,
                          const float* __restrict__ bvec, const float* __restrict__ gvec,
                          const float* __restrict__ evec, float* __restrict__ xout,
                          _Float16* __restrict__ xhout) {
    int wid = threadIdx.x >> 6, lane = threadIdx.x & 63;
    int row = blockIdx.x * 4 + wid;
    if (row >= N_NODES) return;
    const half4* p0 = (const half4*)(hbuf + (size_t)row * 256);
    const half4* p1 = (const half4*)(hbuf + (size_t)M_PAD * 256     + (size_t)row * 256);
    const half4* p2 = (const half4*)(hbuf + (size_t)M_PAD * 256 * 2 + (size_t)row * 256);
    const half4* p3 = (const half4*)(hbuf + (size_t)M_PAD * 256 * 3 + (size_t)row * 256);
    half4 h0 = p0[lane], h1 = p1[lane], h2 = p2[lane], h3 = p3[lane];
    float s1v = s1a[row], s2v = s2a[row];
    float4 bv = ((const float4*)bvec)[lane];
    float4 hv;
    hv.x = (float)h0.x + s1v * (float)h1.x + s2v * (float)h2.x + (float)h3.x + bv.x;
    hv.y = (float)h0.y + s1v * (float)h1.y + s2v * (float)h2.y + (float)h3.y + bv.y;
    hv.z = (float)h0.z + s1v * (float)h1.z + s2v * (float)h2.z + (float)h3.z + bv.z;
    hv.w = (float)h0.w + s1v * (float)h1.w + s2v * (float)h2.w + (float)h3.w + bv.w;
    float s = hv.x + hv.y + hv.z + hv.w;
    float qsq = hv.x*hv.x + hv.y*hv.y + hv.z*hv.z + hv.w*hv.w;
    #pragma unroll
    for (int off = 1; off < 64; off <<= 1) {
        s   += __shfl_xor(s, off);
        qsq += __shfl_xor(qsq, off);
    }
    float mu  = s * (1.0f / 256.0f);
    float var = qsq * (1.0f / 256.0f) - mu * mu;
    float rs  = rsqrtf(var + EPS_LN);
    float4 g = ((const float4*)gvec)[lane];
    float4 e = ((const float4*)evec)[lane];
    float4 xv = ((const float4*)(xin + (size_t)row * 256))[lane];
    float4 o;
    o.x = fmaxf((hv.x - mu) * rs * g.x + e.x, 0.f) + xv.x;
    o.y = fmaxf((hv.y - mu) * rs * g.y + e.y, 0.f) + xv.y;
    o.z = fmaxf((hv.z - mu) * rs * g.z + e.z, 0.f) + xv.z;
    o.w = fmaxf((hv.w - mu) * rs * g.w + e.w, 0.f) + xv.w;
    ((float4*)(xout + (size_t)row * 256))[lane] = o;
    half4 oh = { (_Float16)o.x, (_Float16)o.y, (_Float16)o.z, (_Float16)o.w };
    ((half4*)(xhout + (size_t)row * 256))[lane] = oh;
}

// ---------------- final scoring ----------------
__global__ void score_kernel(const float* __restrict__ x, const float* __restrict__ remb,
                             const int* __restrict__ batch, float* __restrict__ out) {
    int wid = threadIdx.x >> 6, lane = threadIdx.x & 63;
    int g = blockIdx.x * 4 + wid;
    if (g >= B_BATCH * K_BATCH) return;
    int si = batch[g * 3 + 0], ri = batch[g * 3 + 1], ti = batch[g * 3 + 2];
    const float4* xs = (const float4*)(x + (size_t)si * 256);
    const float4* xr = (const float4*)(remb + (size_t)ri * 256);
    const float4* xt = (const float4*)(x + (size_t)ti * 256);
    float4 a = xs[lane], r = xr[lane], t = xt[lane];
    float p = a.x*r.x*t.x + a.y*r.y*t.y + a.z*r.z*t.z + a.w*r.w*t.w;
    #pragma unroll
    for (int off = 1; off < 64; off <<= 1) p += __shfl_xor(p, off);
    if (lane == 0) out[g] = p;
}

extern "C" void kernel_launch(void* const* d_in, const int* in_sizes, int n_in,
                              void* d_out, int out_size, void* d_ws, size_t ws_size,
                              hipStream_t stream) {
    const float* x_in     = (const float*)d_in[0];
    const float* rel_embs = (const float*)d_in[1];
    const float* Ws       = (const float*)d_in[2];
    const float* bs       = (const float*)d_in[3];
    const float* ln_s     = (const float*)d_in[4];
    const float* ln_b     = (const float*)d_in[5];
    const float* remb     = (const float*)d_in[6];
    const int*   eidx     = (const int*)d_in[7];
    const int*   etype    = (const int*)d_in[8];
    const int*   batch    = (const int*)d_in[9];
    float* out = (float*)d_out;

    char* wp = (char*)d_ws;
    size_t o = 0;
    auto alloc = [&](size_t bytes) { void* p = wp + o; o += (bytes + 255) & ~255ull; return p; };
    int*      deg_in  = (int*)     alloc((size_t)N_NODES * 4);
    int*      offs    = (int*)     alloc((size_t)N_NODES * 4);
    int*      cursor  = (int*)     alloc((size_t)N_NODES * 4);
    float*    s1      = (float*)   alloc((size_t)M_PAD * 4);
    float*    s2      = (float*)   alloc((size_t)M_PAD * 4);
    float*    sum_log = (float*)   alloc(256);
    int2*     csr     = (int2*)    alloc((size_t)E_EDGES * 8);
    _Float16* feats   = (_Float16*)alloc((size_t)M_PAD * 1024 * 2);           // 20.7 MB
    _Float16* Wt      = (_Float16*)alloc((size_t)L_LAYERS * WL_STRIDE * 2);   // 10.2 MB
    _Float16* hbuf    = (_Float16*)alloc((size_t)4 * M_PAD * 256 * 2);        // 20.7 MB
    float*    xb0     = (float*)   alloc((size_t)M_PAD * 256 * 4);
    float*    xb1     = (float*)   alloc((size_t)M_PAD * 256 * 4);
    _Float16* xh0     = (_Float16*)alloc((size_t)M_PAD * 256 * 2);
    _Float16* xh1     = (_Float16*)alloc((size_t)M_PAD * 256 * 2);
    _Float16* relh    = (_Float16*)alloc((size_t)L_LAYERS * R_REL * 256 * 2); // 0.73 MB

    const int* src  = eidx;
    const int* dstp = eidx + E_EDGES;

    hipMemsetAsync(deg_in, 0, (size_t)N_NODES * 4, stream);
    hist_kernel<<<(E_EDGES + 255) / 256, 256, 0, stream>>>(dstp, deg_in);
    scan_kernel<<<1, 1024, 0, stream>>>(deg_in, offs, cursor, sum_log);
    fill_kernel<<<(E_EDGES + 255) / 256, 256, 0, stream>>>(src, dstp, etype, cursor, csr);
    scales_kernel<<<(N_NODES + 255) / 256, 256, 0, stream>>>(deg_in, sum_log, s1, s2);
    {
        const int TOT = L_LAYERS * WL_STRIDE;
        wt_kernel<<<(TOT + 255) / 256, 256, 0, stream>>>(Ws, Wt);
        const int RT = L_LAYERS * R_REL * 256;
        cvt_kernel<<<(RT + 255) / 256, 256, 0, stream>>>(rel_embs, relh, RT);
        const int XT = N_NODES * 256;
        cvt_kernel<<<(XT + 255) / 256, 256, 0, stream>>>(x_in, xh0, XT);
    }
    hipMemcpyAsync(xb0, x_in, (size_t)N_NODES * 256 * 4, hipMemcpyDeviceToDevice, stream);

    float* xc = xb0; float* xn = xb1;
    _Float16* xhc = xh0; _Float16* xhn = xh1;
    for (int l = 0; l < L_LAYERS; l++) {
        agg_kernel<<<(N_NODES + 3) / 4, 256, 0, stream>>>(
            xc, xhc, relh + (size_t)l * R_REL * 256,
            offs, deg_in, csr, feats);
        gemm_kernel<<<632, 256, 0, stream>>>(
            feats, xhc, Wt + (size_t)l * WL_STRIDE, hbuf);
        ln_kernel<<<(N_NODES + 3) / 4, 256, 0, stream>>>(
            hbuf, xc, s1, s2, bs + (size_t)l * 256, ln_s + (size_t)l * 256,
            ln_b + (size_t)l * 256, xn, xhn);
        float* t = xc; xc = xn; xn = t;
        _Float16* th = xhc; xhc = xhn; xhn = th;
    }
    score_kernel<<<(B_BATCH * K_BATCH + 3) / 4, 256, 0, stream>>>(xc, remb, batch, out);
}

// Round 16
// 417.763 us; speedup vs baseline: 1.5115x; 1.0389x over previous
//
#include <hip/hip_runtime.h>
#include <math.h>

typedef __attribute__((ext_vector_type(8))) _Float16 half8;
typedef __attribute__((ext_vector_type(4))) _Float16 half4;
typedef __attribute__((ext_vector_type(4))) float    floatx4;
typedef __attribute__((ext_vector_type(2))) float    float2v;

#define N_NODES 10000
#define M_PAD   10112      // 79 * 128
#define MTILES  79
#define E_EDGES 160000
#define DIM     256
#define R_REL   237
#define L_LAYERS 6
#define B_BATCH 128
#define K_BATCH 33
#define K13     3328       // 13*256
#define WL_STRIDE 851968   // per-layer: 3*256*1024 + 256*256 halves
#define EPS_STD 1e-6f
#define EPS_LN  1e-5f

// async global->LDS, 16B per lane; LDS dest = wave-uniform base + lane*16
__device__ __forceinline__ void gload16(const void* g, void* lds) {
    __builtin_amdgcn_global_load_lds(
        (const __attribute__((address_space(1))) unsigned int*)g,
        (__attribute__((address_space(3))) unsigned int*)lds, 16, 0, 0);
}

// packed fp16 max/min (exact)
__device__ __forceinline__ unsigned pkmax16(unsigned a, unsigned b) {
    unsigned r;
    asm("v_pk_max_f16 %0, %1, %2" : "=v"(r) : "v"(a), "v"(b));
    return r;
}
__device__ __forceinline__ unsigned pkmin16(unsigned a, unsigned b) {
    unsigned r;
    asm("v_pk_min_f16 %0, %1, %2" : "=v"(r) : "v"(a), "v"(b));
    return r;
}
typedef union { half8 h; unsigned u[4]; } h8u;

// ---------------- CSR build ----------------
__global__ void hist_kernel(const int* __restrict__ dst, int* __restrict__ deg) {
    int e = blockIdx.x * blockDim.x + threadIdx.x;
    if (e < E_EDGES) atomicAdd(&deg[dst[e]], 1);
}

__global__ void scan_kernel(const int* __restrict__ deg_in, int* __restrict__ offs,
                            int* __restrict__ cursor, float* __restrict__ sum_log) {
    __shared__ int   part[1024];
    __shared__ float slog[1024];
    int t = threadIdx.x;
    const int CH = 10;
    int base = t * CH;
    int lsum = 0; float ls = 0.f;
    for (int j = 0; j < CH; j++) {
        int i = base + j;
        if (i < N_NODES) { int d = deg_in[i]; lsum += d; ls += logf((float)(d + 1)); }
    }
    part[t] = lsum; slog[t] = ls;
    __syncthreads();
    for (int off = 1; off < 1024; off <<= 1) {
        int v = (t >= off) ? part[t - off] : 0;
        __syncthreads();
        part[t] += v;
        __syncthreads();
    }
    int run = part[t] - lsum;
    for (int j = 0; j < CH; j++) {
        int i = base + j;
        if (i < N_NODES) { offs[i] = run; cursor[i] = run; run += deg_in[i]; }
    }
    __syncthreads();
    for (int off = 512; off > 0; off >>= 1) {
        if (t < off) slog[t] += slog[t + off];
        __syncthreads();
    }
    if (t == 0) sum_log[0] = slog[0];
}

__global__ void fill_kernel(const int* __restrict__ src, const int* __restrict__ dst,
                            const int* __restrict__ et, int* __restrict__ cursor,
                            int2* __restrict__ csr) {
    int e = blockIdx.x * blockDim.x + threadIdx.x;
    if (e < E_EDGES) {
        int d = dst[e];
        int p = atomicAdd(&cursor[d], 1);
        csr[p] = make_int2(src[e], et[e]);
    }
}

__global__ void scales_kernel(const int* __restrict__ deg_in, const float* __restrict__ sum_log,
                              float* __restrict__ s1, float* __restrict__ s2) {
    int i = blockIdx.x * blockDim.x + threadIdx.x;
    if (i < N_NODES) {
        float mean = sum_log[0] * (1.0f / (float)N_NODES);
        float sc = logf((float)(deg_in[i] + 1)) / mean;
        s1[i] = sc;
        s2[i] = 1.0f / fmaxf(sc, 0.01f);
    }
}

// -------- W permute+transpose to fp16, LDS-tiled (coalesced read AND write) --------
// out per layer: [s][n][k1024] (korig = k*3+s), then [n][kx256] (korig = 3072+kx)
// grid: per layer 3*16*4 s-blocks + 4*4 x-blocks = 208; total 1248 blocks of 256 thr
__global__ void wt_kernel(const float* __restrict__ Ws, _Float16* __restrict__ Wt) {
    __shared__ float tile[64][65];
    int b = blockIdx.x;
    int l = b / 208;
    int r = b - l * 208;
    int spanel = (r < 192) ? 1 : 0;
    int sidx = 0, kt, nt;
    if (spanel) { sidx = r >> 6; int r2 = r & 63; kt = r2 >> 2; nt = r2 & 3; }
    else        { int r2 = r - 192; kt = r2 >> 2; nt = r2 & 3; }
    int k0 = kt * 64, n0 = nt * 64;
    int tid = threadIdx.x;
    int rr = tid >> 4;      // 0..15
    int cc = tid & 15;      // 0..15
    const float* srcL = Ws + (size_t)l * K13 * 256;
    #pragma unroll
    for (int p = 0; p < 4; p++) {
        int krow = p * 16 + rr;
        int korig = spanel ? (k0 + krow) * 3 + sidx : 3072 + k0 + krow;
        float4 v = *(const float4*)(srcL + (size_t)korig * 256 + n0 + cc * 4);
        tile[krow][cc * 4 + 0] = v.x;
        tile[krow][cc * 4 + 1] = v.y;
        tile[krow][cc * 4 + 2] = v.z;
        tile[krow][cc * 4 + 3] = v.w;
    }
    __syncthreads();
    _Float16* outL = Wt + (size_t)l * WL_STRIDE;
    #pragma unroll
    for (int p = 0; p < 4; p++) {
        int nrow = p * 16 + rr;
        int kk = cc * 4;
        half4 hv = { (_Float16)tile[kk + 0][nrow], (_Float16)tile[kk + 1][nrow],
                     (_Float16)tile[kk + 2][nrow], (_Float16)tile[kk + 3][nrow] };
        size_t oo = spanel ? ((size_t)sidx * 262144 + (size_t)(n0 + nrow) * 1024 + k0 + kk)
                           : ((size_t)786432 + (size_t)(n0 + nrow) * 256 + k0 + kk);
        *(half4*)(outL + oo) = hv;
    }
}

// -------- fp32 -> fp16 converter --------
__global__ void cvt_kernel(const float* __restrict__ in, _Float16* __restrict__ outp, int n) {
    int i = blockIdx.x * 256 + threadIdx.x;
    if (i < n) outp[i] = (_Float16)in[i];
}

// ---- aggregation v3: one wave per node, 2 edges/iter, BRANCHLESS main loop ----
__global__ void agg_kernel(const float* __restrict__ x, const _Float16* __restrict__ xh,
                           const _Float16* __restrict__ relh,
                           const int* __restrict__ offs, const int* __restrict__ deg_in,
                           const int2* __restrict__ csr, _Float16* __restrict__ feats) {
    int wid  = threadIdx.x >> 6;
    int lane = threadIdx.x & 63;
    int node = blockIdx.x * 4 + wid;
    if (node >= N_NODES) return;
    int half = lane >> 5;
    int sub  = lane & 31;
    int off = offs[node];
    int dc  = deg_in[node];
    int npairs = dc >> 1;
    const half8* xh8 = (const half8*)xh;
    const half8* rh8 = (const half8*)relh;

    float2v s2[4], q2[4];
    unsigned mxu[4], mnu[4];
    #pragma unroll
    for (int i = 0; i < 4; i++) {
        s2[i] = (float2v){0.f, 0.f};
        q2[i] = (float2v){0.f, 0.f};
        mxu[i] = 0xFC00FC00u;
        mnu[i] = 0x7C007C00u;
    }

    const int2* ep = csr + off + half;
    for (int p = 0; p < npairs; p++) {
        int2 se = ep[2 * p];
        half8 xv = xh8[(size_t)se.x * 32 + sub];
        half8 rv = rh8[(size_t)se.y * 32 + sub];
        half8 mv = xv * rv;
        h8u mu; mu.h = mv;
        #pragma unroll
        for (int i = 0; i < 4; i++) {
            mxu[i] = pkmax16(mxu[i], mu.u[i]);
            mnu[i] = pkmin16(mnu[i], mu.u[i]);
            float2v mf = { (float)mv[2*i], (float)mv[2*i+1] };
            s2[i] += mf;
            q2[i] += mf * mf;
        }
    }
    if (dc & 1) {
        int2 se = csr[off + dc - 1];
        half8 xv = xh8[(size_t)se.x * 32 + sub];
        half8 rv = rh8[(size_t)se.y * 32 + sub];
        half8 mv = xv * rv;
        h8u mu; mu.h = mv;
        #pragma unroll
        for (int i = 0; i < 4; i++) {
            mxu[i] = pkmax16(mxu[i], mu.u[i]);
            mnu[i] = pkmin16(mnu[i], mu.u[i]);
            float2v mf = { (float)mv[2*i], (float)mv[2*i+1] };
            s2[i] += 0.5f * mf;
            q2[i] += (0.5f * mf) * mf;
        }
    }
    float s_[8], q_[8], mx_[8], mn_[8];
    #pragma unroll
    for (int i = 0; i < 4; i++) {
        mxu[i] = pkmax16(mxu[i], (unsigned)__shfl_xor((int)mxu[i], 32));
        mnu[i] = pkmin16(mnu[i], (unsigned)__shfl_xor((int)mnu[i], 32));
        h8u tx; tx.u[0] = mxu[i]; h8u tn; tn.u[0] = mnu[i];
        mx_[2*i]   = (float)tx.h[0]; mx_[2*i+1] = (float)tx.h[1];
        mn_[2*i]   = (float)tn.h[0]; mn_[2*i+1] = (float)tn.h[1];
        s_[2*i]   = s2[i].x + __shfl_xor(s2[i].x, 32);
        s_[2*i+1] = s2[i].y + __shfl_xor(s2[i].y, 32);
        q_[2*i]   = q2[i].x + __shfl_xor(q2[i].x, 32);
        q_[2*i+1] = q2[i].y + __shfl_xor(q2[i].y, 32);
    }
    const float4* xrow = (const float4*)(x + (size_t)node * 256);
    float4 xa = xrow[sub * 2], xb = xrow[sub * 2 + 1];
    float xs[8] = {xa.x, xa.y, xa.z, xa.w, xb.x, xb.y, xb.z, xb.w};
    #pragma unroll
    for (int i = 0; i < 8; i++) {
        s_[i] += xs[i]; q_[i] += xs[i] * xs[i];
        mx_[i] = fmaxf(mx_[i], xs[i]);
        mn_[i] = fminf(mn_[i], xs[i]);
    }
    float inv = 1.0f / (float)(dc + 1);
    half8 hm, hx, hn, hs;
    #pragma unroll
    for (int i = 0; i < 8; i++) {
        float mean = s_[i] * inv;
        float sd = sqrtf(fmaxf(q_[i] * inv - mean * mean, EPS_STD));
        hm[i] = (_Float16)mean; hx[i] = (_Float16)mx_[i];
        hn[i] = (_Float16)mn_[i]; hs[i] = (_Float16)sd;
    }
    half8* fout = (half8*)(feats + (size_t)node * 1024);
    if (half == 0) {
        fout[0 * 32 + sub] = hm;
        fout[1 * 32 + sub] = hx;
    } else {
        fout[2 * 32 + sub] = hn;
        fout[3 * 32 + sub] = hs;
    }
}

// ---------------- fp16 MFMA GEMM: 4 unscaled panels (G0,G1,G2,Gx), pure gload_lds ----------------
// 128x128 tile, 2x2 waves (64x64 each), 3-buffer counted vmcnt(4).  (round-11 verbatim)
__launch_bounds__(256, 3)
__global__ void gemm_kernel(const _Float16* __restrict__ feats, const _Float16* __restrict__ xh,
                            const _Float16* __restrict__ Wl, _Float16* __restrict__ hbuf) {
    __shared__ _Float16 sA[3][128 * 32];   // 24 KB
    __shared__ _Float16 sB[3][128 * 32];   // 24 KB

    int xcd = blockIdx.x & 7, loc = blockIdx.x >> 3;
    int lin = xcd * MTILES + loc;
    int sidx = lin & 3;
    int nh   = (lin >> 2) & 1;
    int m    = lin >> 3;
    const int i0 = m * 128;
    const int n0 = nh * 128;
    const int NS  = (sidx == 3) ? 8 : 32;
    const int nit = (NS - 2) / 3;

    const int tid   = threadIdx.x;
    const int lane  = tid & 63;
    const int w     = tid >> 6;
    const int wr    = w >> 1;
    const int wc    = w & 1;
    const int row_l = lane & 15;
    const int kq    = lane >> 4;

    int a_off[4], b_off[4];
    #pragma unroll
    for (int rf = 0; rf < 4; rf++) {
        int r = wr * 64 + rf * 16 + row_l;
        a_off[rf] = r * 32 + ((kq ^ ((r >> 1) & 3)) & 3) * 8;
    }
    #pragma unroll
    for (int cf = 0; cf < 4; cf++) {
        int n_ = wc * 64 + cf * 16 + row_l;
        b_off[cf] = n_ * 32 + ((kq ^ ((n_ >> 1) & 3)) & 3) * 8;
    }

    const char* a_src[2];
    const char* b_src[2];
    #pragma unroll
    for (int j = 0; j < 2; j++) {
        int rloc = j * 64 + w * 16 + (lane >> 2);
        int c = (lane & 3) ^ ((rloc >> 1) & 3);
        if (sidx < 3) {
            a_src[j] = (const char*)(feats + (size_t)(i0 + rloc) * 1024 + c * 8);
            b_src[j] = (const char*)(Wl + (size_t)sidx * 262144 + (size_t)(n0 + rloc) * 1024 + c * 8);
        } else {
            a_src[j] = (const char*)(xh + (size_t)(i0 + rloc) * 256 + c * 8);
            b_src[j] = (const char*)(Wl + 786432 + (size_t)(n0 + rloc) * 256 + c * 8);
        }
    }

    floatx4 acc[4][4];
    #pragma unroll
    for (int rf = 0; rf < 4; rf++)
        #pragma unroll
        for (int cf = 0; cf < 4; cf++)
            acc[rf][cf] = (floatx4){0.f, 0.f, 0.f, 0.f};

#define STAGE(BUF, S) do {                                                    \
    size_t koff_ = (size_t)(S) * 64;                                          \
    gload16(a_src[0] + koff_, (char*)(&sA[BUF][0]) + (0 * 64 + w * 16) * 64); \
    gload16(a_src[1] + koff_, (char*)(&sA[BUF][0]) + (1 * 64 + w * 16) * 64); \
    gload16(b_src[0] + koff_, (char*)(&sB[BUF][0]) + (0 * 64 + w * 16) * 64); \
    gload16(b_src[1] + koff_, (char*)(&sB[BUF][0]) + (1 * 64 + w * 16) * 64); \
} while (0)

#define COMPUTE(CB) do {                                                      \
    half8 af[4], bf[4];                                                       \
    _Pragma("unroll")                                                         \
    for (int rf = 0; rf < 4; rf++) af[rf] = *(const half8*)(&sA[CB][a_off[rf]]); \
    _Pragma("unroll")                                                         \
    for (int cf = 0; cf < 4; cf++) bf[cf] = *(const half8*)(&sB[CB][b_off[cf]]); \
    _Pragma("unroll")                                                         \
    for (int rf = 0; rf < 4; rf++)                                            \
        _Pragma("unroll")                                                     \
        for (int cf = 0; cf < 4; cf++)                                        \
            acc[rf][cf] = __builtin_amdgcn_mfma_f32_16x16x32_f16(af[rf], bf[cf], acc[rf][cf], 0, 0, 0); \
} while (0)

#define STEP(S, CB, NB) do {                                                  \
    asm volatile("s_waitcnt vmcnt(4)" ::: "memory");                          \
    __builtin_amdgcn_s_barrier();                                             \
    STAGE(NB, (S) + 2);                                                       \
    COMPUTE(CB);                                                              \
} while (0)

    STAGE(0, 0);
    STAGE(1, 1);

    for (int it = 0; it < nit; ++it) {
        int s = it * 3;
        STEP(s + 0, 0, 2);
        STEP(s + 1, 1, 0);
        STEP(s + 2, 2, 1);
    }
    asm volatile("s_waitcnt vmcnt(4)" ::: "memory");
    __builtin_amdgcn_s_barrier();
    COMPUTE(0);
    asm volatile("s_waitcnt vmcnt(0)" ::: "memory");
    __builtin_amdgcn_s_barrier();
    COMPUTE(1);

#undef STAGE
#undef COMPUTE
#undef STEP

    _Float16* outb = hbuf + (size_t)sidx * M_PAD * 256;
    #pragma unroll
    for (int rf = 0; rf < 4; rf++) {
        #pragma unroll
        for (int j = 0; j < 4; j++) {
            int grow = i0 + wr * 64 + rf * 16 + kq * 4 + j;
            _Float16* orow = outb + (size_t)grow * 256 + n0 + wc * 64;
            #pragma unroll
            for (int cf = 0; cf < 4; cf++)
                orow[cf * 16 + row_l] = (_Float16)acc[rf][cf][j];
        }
    }
}

// ------- panel combine (G0 + s1*G1 + s2*G2 + Gx) + bias + LN + relu + residual -------
__global__ void ln_kernel(const _Float16* __restrict__ hbuf, const float* __restrict__ xin,
                          const float* __restrict__ s1a, const float* __restrict__ s2a,
                          const float* __restrict__ bvec, const float* __restrict__ gvec,
                          const float* __restrict__ evec, float* __restrict__ xout,
                          _Float16* __restrict__ xhout) {
    int wid = threadIdx.x >> 6, lane = threadIdx.x & 63;
    int row = blockIdx.x * 4 + wid;
    if (row >= N_NODES) return;
    const half4* p0 = (const half4*)(hbuf + (size_t)row * 256);
    const half4* p1 = (const half4*)(hbuf + (size_t)M_PAD * 256     + (size_t)row * 256);
    const half4* p2 = (const half4*)(hbuf + (size_t)M_PAD * 256 * 2 + (size_t)row * 256);
    const half4* p3 = (const half4*)(hbuf + (size_t)M_PAD * 256 * 3 + (size_t)row * 256);
    half4 h0 = p0[lane], h1 = p1[lane], h2 = p2[lane], h3 = p3[lane];
    float s1v = s1a[row], s2v = s2a[row];
    float4 bv = ((const float4*)bvec)[lane];
    float4 hv;
    hv.x = (float)h0.x + s1v * (float)h1.x + s2v * (float)h2.x + (float)h3.x + bv.x;
    hv.y = (float)h0.y + s1v * (float)h1.y + s2v * (float)h2.y + (float)h3.y + bv.y;
    hv.z = (float)h0.z + s1v * (float)h1.z + s2v * (float)h2.z + (float)h3.z + bv.z;
    hv.w = (float)h0.w + s1v * (float)h1.w + s2v * (float)h2.w + (float)h3.w + bv.w;
    float s = hv.x + hv.y + hv.z + hv.w;
    float qsq = hv.x*hv.x + hv.y*hv.y + hv.z*hv.z + hv.w*hv.w;
    #pragma unroll
    for (int off = 1; off < 64; off <<= 1) {
        s   += __shfl_xor(s, off);
        qsq += __shfl_xor(qsq, off);
    }
    float mu  = s * (1.0f / 256.0f);
    float var = qsq * (1.0f / 256.0f) - mu * mu;
    float rs  = rsqrtf(var + EPS_LN);
    float4 g = ((const float4*)gvec)[lane];
    float4 e = ((const float4*)evec)[lane];
    float4 xv = ((const float4*)(xin + (size_t)row * 256))[lane];
    float4 o;
    o.x = fmaxf((hv.x - mu) * rs * g.x + e.x, 0.f) + xv.x;
    o.y = fmaxf((hv.y - mu) * rs * g.y + e.y, 0.f) + xv.y;
    o.z = fmaxf((hv.z - mu) * rs * g.z + e.z, 0.f) + xv.z;
    o.w = fmaxf((hv.w - mu) * rs * g.w + e.w, 0.f) + xv.w;
    ((float4*)(xout + (size_t)row * 256))[lane] = o;
    half4 oh = { (_Float16)o.x, (_Float16)o.y, (_Float16)o.z, (_Float16)o.w };
    ((half4*)(xhout + (size_t)row * 256))[lane] = oh;
}

// ---------------- final scoring ----------------
__global__ void score_kernel(const float* __restrict__ x, const float* __restrict__ remb,
                             const int* __restrict__ batch, float* __restrict__ out) {
    int wid = threadIdx.x >> 6, lane = threadIdx.x & 63;
    int g = blockIdx.x * 4 + wid;
    if (g >= B_BATCH * K_BATCH) return;
    int si = batch[g * 3 + 0], ri = batch[g * 3 + 1], ti = batch[g * 3 + 2];
    const float4* xs = (const float4*)(x + (size_t)si * 256);
    const float4* xr = (const float4*)(remb + (size_t)ri * 256);
    const float4* xt = (const float4*)(x + (size_t)ti * 256);
    float4 a = xs[lane], r = xr[lane], t = xt[lane];
    float p = a.x*r.x*t.x + a.y*r.y*t.y + a.z*r.z*t.z + a.w*r.w*t.w;
    #pragma unroll
    for (int off = 1; off < 64; off <<= 1) p += __shfl_xor(p, off);
    if (lane == 0) out[g] = p;
}

extern "C" void kernel_launch(void* const* d_in, const int* in_sizes, int n_in,
                              void* d_out, int out_size, void* d_ws, size_t ws_size,
                              hipStream_t stream) {
    const float* x_in     = (const float*)d_in[0];
    const float* rel_embs = (const float*)d_in[1];
    const float* Ws       = (const float*)d_in[2];
    const float* bs       = (const float*)d_in[3];
    const float* ln_s     = (const float*)d_in[4];
    const float* ln_b     = (const float*)d_in[5];
    const float* remb     = (const float*)d_in[6];
    const int*   eidx     = (const int*)d_in[7];
    const int*   etype    = (const int*)d_in[8];
    const int*   batch    = (const int*)d_in[9];
    float* out = (float*)d_out;

    char* wp = (char*)d_ws;
    size_t o = 0;
    auto alloc = [&](size_t bytes) { void* p = wp + o; o += (bytes + 255) & ~255ull; return p; };
    int*      deg_in  = (int*)     alloc((size_t)N_NODES * 4);
    int*      offs    = (int*)     alloc((size_t)N_NODES * 4);
    int*      cursor  = (int*)     alloc((size_t)N_NODES * 4);
    float*    s1      = (float*)   alloc((size_t)M_PAD * 4);
    float*    s2      = (float*)   alloc((size_t)M_PAD * 4);
    float*    sum_log = (float*)   alloc(256);
    int2*     csr     = (int2*)    alloc((size_t)E_EDGES * 8);
    _Float16* feats   = (_Float16*)alloc((size_t)M_PAD * 1024 * 2);           // 20.7 MB
    _Float16* Wt      = (_Float16*)alloc((size_t)L_LAYERS * WL_STRIDE * 2);   // 10.2 MB
    _Float16* hbuf    = (_Float16*)alloc((size_t)4 * M_PAD * 256 * 2);        // 20.7 MB
    float*    xb0     = (float*)   alloc((size_t)M_PAD * 256 * 4);
    float*    xb1     = (float*)   alloc((size_t)M_PAD * 256 * 4);
    _Float16* xh0     = (_Float16*)alloc((size_t)M_PAD * 256 * 2);
    _Float16* xh1     = (_Float16*)alloc((size_t)M_PAD * 256 * 2);
    _Float16* relh    = (_Float16*)alloc((size_t)L_LAYERS * R_REL * 256 * 2); // 0.73 MB

    const int* src  = eidx;
    const int* dstp = eidx + E_EDGES;

    hipMemsetAsync(deg_in, 0, (size_t)N_NODES * 4, stream);
    hist_kernel<<<(E_EDGES + 255) / 256, 256, 0, stream>>>(dstp, deg_in);
    scan_kernel<<<1, 1024, 0, stream>>>(deg_in, offs, cursor, sum_log);
    fill_kernel<<<(E_EDGES + 255) / 256, 256, 0, stream>>>(src, dstp, etype, cursor, csr);
    scales_kernel<<<(N_NODES + 255) / 256, 256, 0, stream>>>(deg_in, sum_log, s1, s2);
    {
        wt_kernel<<<L_LAYERS * 208, 256, 0, stream>>>(Ws, Wt);
        const int RT = L_LAYERS * R_REL * 256;
        cvt_kernel<<<(RT + 255) / 256, 256, 0, stream>>>(rel_embs, relh, RT);
        const int XT = N_NODES * 256;
        cvt_kernel<<<(XT + 255) / 256, 256, 0, stream>>>(x_in, xh0, XT);
    }
    hipMemcpyAsync(xb0, x_in, (size_t)N_NODES * 256 * 4, hipMemcpyDeviceToDevice, stream);

    float* xc = xb0; float* xn = xb1;
    _Float16* xhc = xh0; _Float16* xhn = xh1;
    for (int l = 0; l < L_LAYERS; l++) {
        agg_kernel<<<(N_NODES + 3) / 4, 256, 0, stream>>>(
            xc, xhc, relh + (size_t)l * R_REL * 256,
            offs, deg_in, csr, feats);
        gemm_kernel<<<632, 256, 0, stream>>>(
            feats, xhc, Wt + (size_t)l * WL_STRIDE, hbuf);
        ln_kernel<<<(N_NODES + 3) / 4, 256, 0, stream>>>(
            hbuf, xc, s1, s2, bs + (size_t)l * 256, ln_s + (size_t)l * 256,
            ln_b + (size_t)l * 256, xn, xhn);
        float* t = xc; xc = xn; xn = t;
        _Float16* th = xhc; xhc = xhn; xhn = th;
    }
    score_kernel<<<(B_BATCH * K_BATCH + 3) / 4, 256, 0, stream>>>(xc, remb, batch, out);
}